// Round 1
// baseline (372.263 us; speedup 1.0000x reference)
//
#include <hip/hip_runtime.h>

#define B_    8
#define V_    50000
#define KNB   9
#define CIN_  64
#define COUT_ 128
#define VOUT_ 12500
#define NNZ_  37500
#define KTOT  576      // KNB*CIN_
#define M_    400000   // B_*V_

typedef short bf16x8 __attribute__((ext_vector_type(8)));
typedef float f32x4  __attribute__((ext_vector_type(4)));

__device__ __forceinline__ unsigned short f2bf(float f) {
  unsigned u = __float_as_uint(f);
  u += 0x7fffu + ((u >> 16) & 1u);          // RNE
  return (unsigned short)(u >> 16);
}
__device__ __forceinline__ unsigned pack2(float lo, float hi) {
  return (unsigned)f2bf(lo) | ((unsigned)f2bf(hi) << 16);
}

__global__ __launch_bounds__(256) void convert_w(const float* __restrict__ w,
                                                 unsigned short* __restrict__ wbf) {
  int i = blockIdx.x * 256 + threadIdx.x;
  if (i < COUT_ * KTOT) wbf[i] = f2bf(w[i]);
}

// h[m][c] = elu( sum_k A[m][k] * W[c][k] + bias[c] ),  A gathered from x via spiral_indices.
// 128x128 tile, 4 waves (2x2 of 64x64), BK=64 (= one spiral neighbor), 16x16x32 bf16 MFMA.
// LDS rows are 128B => XOR-swizzle byte ^= (row&7)<<4 on both write and read (G4 / rule #21).
__global__ __launch_bounds__(256) void spiral_gemm(
    const float* __restrict__ x, const unsigned short* __restrict__ wbf,
    const float* __restrict__ bias, const int* __restrict__ sp,
    float* __restrict__ h)
{
  __shared__ char As[128 * 128];   // 128 rows x 64 bf16 (128B), swizzled
  __shared__ char Bt[128 * 128];   // 128 cols x 64 bf16 (128B), swizzled

  const int tid = threadIdx.x;
  const int m0  = blockIdx.x * 128;

  // staging role: 2 threads per row, 32 fp32 each
  const int sr = tid >> 1;          // 0..127
  const int hh = tid & 1;
  const int sm = m0 + sr;
  const int sb = sm / V_;
  const int sv = sm - sb * V_;
  const float* xb = x + (size_t)sb * V_ * CIN_;
  const int* sprow = sp + (size_t)sv * KNB;
  const int sswz = (sr & 7) << 4;
  char* aw = As + sr * 128;
  char* bw = Bt + sr * 128;
  const unsigned short* wrow = wbf + (size_t)sr * KTOT + hh * 32;

  // compute role: wave (wr,wc) owns 64x64; per-lane frag coords
  const int wave = tid >> 6;
  const int wr = wave >> 1, wc = wave & 1;
  const int lane = tid & 63;
  const int lr = lane & 15;
  const int lg = lane >> 4;

  f32x4 acc[4][4];
  #pragma unroll
  for (int i = 0; i < 4; ++i)
    #pragma unroll
    for (int j = 0; j < 4; ++j)
      acc[i][j] = (f32x4){0.f, 0.f, 0.f, 0.f};

  for (int t = 0; t < KNB; ++t) {
    { // ---- stage A: gathered x row, fp32 -> bf16, swizzled LDS write
      int idx = sprow[t];
      const float4* src = reinterpret_cast<const float4*>(xb + (size_t)idx * CIN_ + hh * 32);
      unsigned up[16];
      #pragma unroll
      for (int p = 0; p < 8; ++p) {
        float4 f = src[p];
        up[2*p]   = pack2(f.x, f.y);
        up[2*p+1] = pack2(f.z, f.w);
      }
      #pragma unroll
      for (int u = 0; u < 4; ++u) {
        uint4 val = make_uint4(up[4*u], up[4*u+1], up[4*u+2], up[4*u+3]);
        *reinterpret_cast<uint4*>(aw + ((hh * 64 + u * 16) ^ sswz)) = val;
      }
    }
    { // ---- stage B: Bt[col][k] = W[col][t*64+k] (pre-converted bf16, [cout][k] layout)
      const uint4* wsrc = reinterpret_cast<const uint4*>(wrow + t * 64);
      #pragma unroll
      for (int u = 0; u < 4; ++u)
        *reinterpret_cast<uint4*>(bw + ((hh * 64 + u * 16) ^ sswz)) = wsrc[u];
    }
    __syncthreads();
    // ---- MFMA: 2 k-blocks of 32, 4x4 frags per wave
    #pragma unroll
    for (int ks = 0; ks < 2; ++ks) {
      const int kb = ks * 64 + lg * 16;   // byte offset of this lane-group's 8 bf16
      bf16x8 af[4], bfr[4];
      #pragma unroll
      for (int m = 0; m < 4; ++m) {
        int row = wr * 64 + m * 16 + lr;
        af[m] = *reinterpret_cast<const bf16x8*>(As + row * 128 + (kb ^ ((row & 7) << 4)));
      }
      #pragma unroll
      for (int n = 0; n < 4; ++n) {
        int col = wc * 64 + n * 16 + lr;
        bfr[n] = *reinterpret_cast<const bf16x8*>(Bt + col * 128 + (kb ^ ((col & 7) << 4)));
      }
      #pragma unroll
      for (int m = 0; m < 4; ++m)
        #pragma unroll
        for (int n = 0; n < 4; ++n)
          acc[m][n] = __builtin_amdgcn_mfma_f32_16x16x32_bf16(af[m], bfr[n], acc[m][n], 0, 0, 0);
    }
    __syncthreads();
  }

  // ---- epilogue: bias + ELU, store h (C/D layout: col=lane&15, row=(lane>>4)*4+j)
  #pragma unroll
  for (int n = 0; n < 4; ++n) {
    const int c = wc * 64 + n * 16 + lr;
    const float bv = bias[c];
    #pragma unroll
    for (int m = 0; m < 4; ++m) {
      #pragma unroll
      for (int j = 0; j < 4; ++j) {
        const int grow = m0 + wr * 64 + m * 16 + lg * 4 + j;
        float vv = acc[m][n][j] + bv;
        h[(size_t)grow * COUT_ + c] = vv > 0.f ? vv : expm1f(vv);
      }
    }
  }
}

// out[b,row,:] += data * h[b,col,:]; one block per nnz entry, loop over batch.
__global__ __launch_bounds__(128) void pool_scatter(
    const float* __restrict__ h, const int* __restrict__ dr,
    const int* __restrict__ dc, const float* __restrict__ dd,
    float* __restrict__ out)
{
  const int e = blockIdx.x;
  const int c = threadIdx.x;
  const int r  = dr[e];
  const int co = dc[e];
  const float d = dd[e];
  const float* hp = h   + (size_t)co * COUT_ + c;
  float*       op = out + (size_t)r  * COUT_ + c;
  #pragma unroll
  for (int b = 0; b < B_; ++b)
    atomicAdd(op + (size_t)b * (VOUT_ * COUT_), d * hp[(size_t)b * (V_ * COUT_)]);
}

extern "C" void kernel_launch(void* const* d_in, const int* in_sizes, int n_in,
                              void* d_out, int out_size, void* d_ws, size_t ws_size,
                              hipStream_t stream) {
  const float* x    = (const float*)d_in[0];
  const float* w    = (const float*)d_in[1];
  const float* bias = (const float*)d_in[2];
  const int*   sp   = (const int*)d_in[3];
  const int*   dr   = (const int*)d_in[4];
  const int*   dc   = (const int*)d_in[5];
  const float* dd   = (const float*)d_in[6];
  float* out = (float*)d_out;

  unsigned short* wbf = (unsigned short*)d_ws;                  // 147456 B
  float* h = (float*)((char*)d_ws + 147456);                    // 204.8 MB

  convert_w<<<288, 256, 0, stream>>>(w, wbf);
  spiral_gemm<<<M_ / 128, 256, 0, stream>>>(x, wbf, bias, sp, h);
  hipMemsetAsync(d_out, 0, (size_t)out_size * sizeof(float), stream);
  pool_scatter<<<NNZ_, 128, 0, stream>>>(h, dr, dc, dd, out);
}

// Round 2
// 282.775 us; speedup vs baseline: 1.3165x; 1.3165x over previous
//
#include <hip/hip_runtime.h>

#define B_    8
#define V_    50000
#define KNB   9
#define CIN_  64
#define COUT_ 128
#define VOUT_ 12500
#define NNZ_  37500
#define KTOT  576      // KNB*CIN_
#define M_    400000   // B_*V_

typedef short bf16x8 __attribute__((ext_vector_type(8)));
typedef float f32x4  __attribute__((ext_vector_type(4)));

#define AS1 __attribute__((address_space(1)))
#define AS3 __attribute__((address_space(3)))

__device__ __forceinline__ unsigned short f2bf(float f) {
  unsigned u = __float_as_uint(f);
  u += 0x7fffu + ((u >> 16) & 1u);          // RNE
  return (unsigned short)(u >> 16);
}

__device__ __forceinline__ void gld_lds16(const void* g, void* l) {
  __builtin_amdgcn_global_load_lds((const AS1 unsigned*)g, (AS3 unsigned*)l, 16, 0, 0);
}

__global__ __launch_bounds__(256) void convert_w(const float* __restrict__ w,
                                                 unsigned short* __restrict__ wbf) {
  int i = blockIdx.x * 256 + threadIdx.x;   // grid sized exactly to COUT_*KTOT
  wbf[i] = f2bf(w[i]);
}

__global__ __launch_bounds__(256) void convert_x(const float* __restrict__ x,
                                                 unsigned short* __restrict__ xbf) {
  const int nq = B_ * V_ * CIN_ / 4;        // 6.4M float4 quads
  for (int q = blockIdx.x * 256 + threadIdx.x; q < nq; q += 2048 * 256) {
    float4 f = reinterpret_cast<const float4*>(x)[q];
    ushort4 o;
    o.x = f2bf(f.x); o.y = f2bf(f.y); o.z = f2bf(f.z); o.w = f2bf(f.w);
    reinterpret_cast<ushort4*>(xbf)[q] = o;
  }
}

// h[m][c] = elu( sum_k A[m][k]*W[c][k] + bias[c] ), A gathered (bf16) via spiral_indices.
// 128x128 tile, 4 waves, BK=64, double-buffered LDS, global_load_lds staging with
// pre-swizzled global source (rule #21), 2-phase prefetch (T3-lite).
__global__ __launch_bounds__(256) void spiral_gemm(
    const unsigned short* __restrict__ xbf, const unsigned short* __restrict__ wbf,
    const float* __restrict__ bias, const int* __restrict__ sp,
    unsigned short* __restrict__ hbf)
{
  __shared__ char smem[65536];
  char* const Abuf = smem;           // [2][16384] : 128 rows x 64 bf16, swizzled
  char* const Bbuf = smem + 32768;   // [2][16384] : 128 cols x 64 bf16, swizzled

  const int tid  = threadIdx.x;
  const int m0   = blockIdx.x * 128;
  const int wave = tid >> 6;

  // ---- staging geometry: 4 rounds x 32 rows, 8 chunks of 16B per 128B row
  const int rrow  = tid >> 3;                      // 0..31
  const int chunk = tid & 7;
  const int chunkoff = ((chunk ^ (rrow & 7)) << 4); // inverse-swizzled source chunk

  const unsigned short* xbase[4];
  const int* spb[4];
  const char* wcb[4];
  int ldsoff[4];
  #pragma unroll
  for (int r = 0; r < 4; ++r) {
    int row = r * 32 + rrow;
    int m = m0 + row;
    int b = m / V_;
    int v = m - b * V_;
    xbase[r] = xbf + (size_t)b * (V_ * CIN_);
    spb[r]   = sp + v * KNB;
    wcb[r]   = (const char*)wbf + (size_t)row * (KTOT * 2) + chunkoff;
    ldsoff[r] = (r * 32 + wave * 8) * 128;         // wave-uniform LDS base per round
  }

  // ---- compute geometry
  const int wr = wave >> 1, wc = wave & 1;
  const int lane = tid & 63;
  const int lr = lane & 15, lg = lane >> 4;
  int aoff[4], aswz[4], boff[4], bswz[4];
  #pragma unroll
  for (int m = 0; m < 4; ++m) {
    int row = wr * 64 + m * 16 + lr;
    aoff[m] = row * 128; aswz[m] = (row & 7) << 4;
    int col = wc * 64 + m * 16 + lr;
    boff[m] = col * 128; bswz[m] = (col & 7) << 4;
  }

  f32x4 acc[4][4];
  #pragma unroll
  for (int i = 0; i < 4; ++i)
    #pragma unroll
    for (int j = 0; j < 4; ++j)
      acc[i][j] = (f32x4){0.f, 0.f, 0.f, 0.f};

  auto stage = [&](int buf, int t, const int (&idx)[4]) {
    char* Ab = Abuf + buf * 16384;
    char* Bb = Bbuf + buf * 16384;
    #pragma unroll
    for (int r = 0; r < 4; ++r) {
      const char* ga = (const char*)xbase[r] + (size_t)idx[r] * 128 + chunkoff;
      gld_lds16(ga, Ab + ldsoff[r]);
      gld_lds16(wcb[r] + t * 128, Bb + ldsoff[r]);
    }
  };

  auto compute = [&](int buf) {
    const char* Ab = Abuf + buf * 16384;
    const char* Bb = Bbuf + buf * 16384;
    #pragma unroll
    for (int ks = 0; ks < 2; ++ks) {
      const int kb = ks * 64 + lg * 16;
      bf16x8 af[4], bfr[4];
      #pragma unroll
      for (int m = 0; m < 4; ++m)
        af[m] = *reinterpret_cast<const bf16x8*>(Ab + aoff[m] + (kb ^ aswz[m]));
      #pragma unroll
      for (int n = 0; n < 4; ++n)
        bfr[n] = *reinterpret_cast<const bf16x8*>(Bb + boff[n] + (kb ^ bswz[n]));
      #pragma unroll
      for (int m = 0; m < 4; ++m)
        #pragma unroll
        for (int n = 0; n < 4; ++n)
          acc[m][n] = __builtin_amdgcn_mfma_f32_16x16x32_bf16(af[m], bfr[n], acc[m][n], 0, 0, 0);
    }
  };

  // ---- prologue
  int idx[4], nidx[4];
  #pragma unroll
  for (int r = 0; r < 4; ++r) idx[r] = spb[r][0];
  stage(0, 0, idx);
  #pragma unroll
  for (int r = 0; r < 4; ++r) nidx[r] = spb[r][1];
  __syncthreads();   // compiler drains vmcnt(0) here

  // ---- main loop: prefetch t+1 before compute(t)
  int cur = 0;
  for (int t = 0; t < KNB; ++t) {
    if (t < KNB - 1) {
      stage(cur ^ 1, t + 1, nidx);
      if (t < KNB - 2) {
        #pragma unroll
        for (int r = 0; r < 4; ++r) nidx[r] = spb[r][t + 2];
      }
    }
    compute(cur);
    __syncthreads();
    cur ^= 1;
  }

  // ---- epilogue: bias + ELU -> bf16, re-layout via LDS for coalesced 16B stores
  unsigned short* hs = (unsigned short*)smem;   // [128][136] (pad: 272B row, 16-aligned)
  #pragma unroll
  for (int n = 0; n < 4; ++n) {
    const int c = wc * 64 + n * 16 + lr;
    const float bv = bias[c];
    #pragma unroll
    for (int m = 0; m < 4; ++m) {
      const int row = wr * 64 + m * 16 + lg * 4;
      #pragma unroll
      for (int j = 0; j < 4; ++j) {
        float vv = acc[m][n][j] + bv;
        vv = vv > 0.f ? vv : (__expf(vv) - 1.f);
        hs[(row + j) * 136 + c] = f2bf(vv);
      }
    }
  }
  __syncthreads();
  const int r2 = tid >> 1, hf = tid & 1;
  const uint4* srow = reinterpret_cast<const uint4*>((const char*)hs + r2 * 272 + hf * 128);
  uint4* drow = reinterpret_cast<uint4*>(hbf + (size_t)(m0 + r2) * COUT_ + hf * 64);
  #pragma unroll
  for (int u = 0; u < 8; ++u) drow[u] = srow[u];
}

// out[b,row,:] += data * h[b,col,:]; one block per nnz entry, loop over batch.
__global__ __launch_bounds__(128) void pool_scatter(
    const unsigned short* __restrict__ hbf, const int* __restrict__ dr,
    const int* __restrict__ dc, const float* __restrict__ dd,
    float* __restrict__ out)
{
  const int e = blockIdx.x;
  const int c = threadIdx.x;
  const int r  = dr[e];
  const int co = dc[e];
  const float d = dd[e];
  const unsigned short* hp = hbf + (size_t)co * COUT_ + c;
  float*       op = out + (size_t)r * COUT_ + c;
  #pragma unroll
  for (int b = 0; b < B_; ++b) {
    float f = __uint_as_float((unsigned)hp[(size_t)b * (V_ * COUT_)] << 16);
    atomicAdd(op + (size_t)b * (VOUT_ * COUT_), d * f);
  }
}

extern "C" void kernel_launch(void* const* d_in, const int* in_sizes, int n_in,
                              void* d_out, int out_size, void* d_ws, size_t ws_size,
                              hipStream_t stream) {
  const float* x    = (const float*)d_in[0];
  const float* w    = (const float*)d_in[1];
  const float* bias = (const float*)d_in[2];
  const int*   sp   = (const int*)d_in[3];
  const int*   dr   = (const int*)d_in[4];
  const int*   dc   = (const int*)d_in[5];
  const float* dd   = (const float*)d_in[6];
  float* out = (float*)d_out;

  unsigned short* wbf = (unsigned short*)d_ws;                          // 147456 B
  unsigned short* xbf = (unsigned short*)((char*)d_ws + 147456);        // 51.2 MB
  unsigned short* hbf = (unsigned short*)((char*)d_ws + 147456 + 51200000); // 102.4 MB

  convert_w<<<288, 256, 0, stream>>>(w, wbf);
  convert_x<<<2048, 256, 0, stream>>>(x, xbf);
  hipMemsetAsync(d_out, 0, (size_t)out_size * sizeof(float), stream);
  spiral_gemm<<<M_ / 128, 256, 0, stream>>>(xbf, wbf, bias, sp, hbf);
  pool_scatter<<<NNZ_, 128, 0, stream>>>(hbf, dr, dc, dd, out);
}

// Round 3
// 213.052 us; speedup vs baseline: 1.7473x; 1.3273x over previous
//
#include <hip/hip_runtime.h>

#define B_    8
#define V_    50000
#define KNB   9
#define CIN_  64
#define COUT_ 128
#define VOUT_ 12500
#define NNZ_  37500
#define KTOT  576      // KNB*CIN_
#define M_    400000   // B_*V_

typedef short bf16x8 __attribute__((ext_vector_type(8)));
typedef float f32x4  __attribute__((ext_vector_type(4)));

#define AS1 __attribute__((address_space(1)))
#define AS3 __attribute__((address_space(3)))

__device__ __forceinline__ unsigned short f2bf(float f) {
  unsigned u = __float_as_uint(f);
  u += 0x7fffu + ((u >> 16) & 1u);          // RNE
  return (unsigned short)(u >> 16);
}
__device__ __forceinline__ float bf2f(unsigned short u) {
  return __uint_as_float((unsigned)u << 16);
}

__device__ __forceinline__ void gld_lds16(const void* g, void* l) {
  __builtin_amdgcn_global_load_lds((const AS1 unsigned*)g, (AS3 unsigned*)l, 16, 0, 0);
}

__global__ __launch_bounds__(256) void convert_w(const float* __restrict__ w,
                                                 unsigned short* __restrict__ wbf) {
  int i = blockIdx.x * 256 + threadIdx.x;   // grid sized exactly to COUT_*KTOT
  wbf[i] = f2bf(w[i]);
}

__global__ __launch_bounds__(256) void convert_x(const float* __restrict__ x,
                                                 unsigned short* __restrict__ xbf) {
  const int nq = B_ * V_ * CIN_ / 4;        // 6.4M float4 quads
  for (int q = blockIdx.x * 256 + threadIdx.x; q < nq; q += 2048 * 256) {
    float4 f = reinterpret_cast<const float4*>(x)[q];
    ushort4 o;
    o.x = f2bf(f.x); o.y = f2bf(f.y); o.z = f2bf(f.z); o.w = f2bf(f.w);
    reinterpret_cast<ushort4*>(xbf)[q] = o;
  }
}

// h[m][c] = elu( sum_k A[m][k]*W[c][k] + bias[c] ), A gathered (bf16) via spiral_indices.
// 128x128 tile, 4 waves, BK=64, double-buffered LDS, global_load_lds staging with
// pre-swizzled global source (rule #21), 2-phase prefetch (T3-lite).
__global__ __launch_bounds__(256) void spiral_gemm(
    const unsigned short* __restrict__ xbf, const unsigned short* __restrict__ wbf,
    const float* __restrict__ bias, const int* __restrict__ sp,
    unsigned short* __restrict__ hbf)
{
  __shared__ char smem[65536];
  char* const Abuf = smem;           // [2][16384] : 128 rows x 64 bf16, swizzled
  char* const Bbuf = smem + 32768;   // [2][16384] : 128 cols x 64 bf16, swizzled

  const int tid  = threadIdx.x;
  const int m0   = blockIdx.x * 128;
  const int wave = tid >> 6;

  // ---- staging geometry: 4 rounds x 32 rows, 8 chunks of 16B per 128B row
  const int rrow  = tid >> 3;                      // 0..31
  const int chunk = tid & 7;
  const int chunkoff = ((chunk ^ (rrow & 7)) << 4); // inverse-swizzled source chunk

  const unsigned short* xbase[4];
  const int* spb[4];
  const char* wcb[4];
  int ldsoff[4];
  #pragma unroll
  for (int r = 0; r < 4; ++r) {
    int row = r * 32 + rrow;
    int m = m0 + row;
    int b = m / V_;
    int v = m - b * V_;
    xbase[r] = xbf + (size_t)b * (V_ * CIN_);
    spb[r]   = sp + v * KNB;
    wcb[r]   = (const char*)wbf + (size_t)row * (KTOT * 2) + chunkoff;
    ldsoff[r] = (r * 32 + wave * 8) * 128;         // wave-uniform LDS base per round
  }

  // ---- compute geometry
  const int wr = wave >> 1, wc = wave & 1;
  const int lane = tid & 63;
  const int lr = lane & 15, lg = lane >> 4;
  int aoff[4], aswz[4], boff[4], bswz[4];
  #pragma unroll
  for (int m = 0; m < 4; ++m) {
    int row = wr * 64 + m * 16 + lr;
    aoff[m] = row * 128; aswz[m] = (row & 7) << 4;
    int col = wc * 64 + m * 16 + lr;
    boff[m] = col * 128; bswz[m] = (col & 7) << 4;
  }

  f32x4 acc[4][4];
  #pragma unroll
  for (int i = 0; i < 4; ++i)
    #pragma unroll
    for (int j = 0; j < 4; ++j)
      acc[i][j] = (f32x4){0.f, 0.f, 0.f, 0.f};

  auto stage = [&](int buf, int t, const int (&idx)[4]) {
    char* Ab = Abuf + buf * 16384;
    char* Bb = Bbuf + buf * 16384;
    #pragma unroll
    for (int r = 0; r < 4; ++r) {
      const char* ga = (const char*)xbase[r] + (size_t)idx[r] * 128 + chunkoff;
      gld_lds16(ga, Ab + ldsoff[r]);
      gld_lds16(wcb[r] + t * 128, Bb + ldsoff[r]);
    }
  };

  auto compute = [&](int buf) {
    const char* Ab = Abuf + buf * 16384;
    const char* Bb = Bbuf + buf * 16384;
    #pragma unroll
    for (int ks = 0; ks < 2; ++ks) {
      const int kb = ks * 64 + lg * 16;
      bf16x8 af[4], bfr[4];
      #pragma unroll
      for (int m = 0; m < 4; ++m)
        af[m] = *reinterpret_cast<const bf16x8*>(Ab + aoff[m] + (kb ^ aswz[m]));
      #pragma unroll
      for (int n = 0; n < 4; ++n)
        bfr[n] = *reinterpret_cast<const bf16x8*>(Bb + boff[n] + (kb ^ bswz[n]));
      #pragma unroll
      for (int m = 0; m < 4; ++m)
        #pragma unroll
        for (int n = 0; n < 4; ++n)
          acc[m][n] = __builtin_amdgcn_mfma_f32_16x16x32_bf16(af[m], bfr[n], acc[m][n], 0, 0, 0);
    }
  };

  // ---- prologue
  int idx[4], nidx[4];
  #pragma unroll
  for (int r = 0; r < 4; ++r) idx[r] = spb[r][0];
  stage(0, 0, idx);
  #pragma unroll
  for (int r = 0; r < 4; ++r) nidx[r] = spb[r][1];
  __syncthreads();   // compiler drains vmcnt(0) here

  // ---- main loop: prefetch t+1 before compute(t)
  int cur = 0;
  for (int t = 0; t < KNB; ++t) {
    if (t < KNB - 1) {
      stage(cur ^ 1, t + 1, nidx);
      if (t < KNB - 2) {
        #pragma unroll
        for (int r = 0; r < 4; ++r) nidx[r] = spb[r][t + 2];
      }
    }
    compute(cur);
    __syncthreads();
    cur ^= 1;
  }

  // ---- epilogue: bias + ELU -> bf16, re-layout via LDS for coalesced 16B stores
  unsigned short* hs = (unsigned short*)smem;   // [128][136] (pad: 272B row, 16-aligned)
  #pragma unroll
  for (int n = 0; n < 4; ++n) {
    const int c = wc * 64 + n * 16 + lr;
    const float bv = bias[c];
    #pragma unroll
    for (int m = 0; m < 4; ++m) {
      const int row = wr * 64 + m * 16 + lg * 4;
      #pragma unroll
      for (int j = 0; j < 4; ++j) {
        float vv = acc[m][n][j] + bv;
        vv = vv > 0.f ? vv : (__expf(vv) - 1.f);
        hs[(row + j) * 136 + c] = f2bf(vv);
      }
    }
  }
  __syncthreads();
  const int r2 = tid >> 1, hf = tid & 1;
  const uint4* srow = reinterpret_cast<const uint4*>((const char*)hs + r2 * 272 + hf * 128);
  uint4* drow = reinterpret_cast<uint4*>(hbf + (size_t)(m0 + r2) * COUT_ + hf * 64);
  #pragma unroll
  for (int u = 0; u < 8; ++u) drow[u] = srow[u];
}

// ---------------- pool: CSR build (count / scan / fill), then row-major gather ----------

__global__ __launch_bounds__(256) void pool_count(const int* __restrict__ dr,
                                                  int* __restrict__ counts) {
  int e = blockIdx.x * 256 + threadIdx.x;
  if (e < NNZ_) atomicAdd(&counts[dr[e]], 1);
}

__global__ __launch_bounds__(1024) void pool_scan(const int* __restrict__ counts,
                                                  int* __restrict__ offsets,
                                                  int* __restrict__ cursor) {
  __shared__ int sh[1024];
  __shared__ int carry;
  if (threadIdx.x == 0) carry = 0;
  __syncthreads();
  for (int base = 0; base < VOUT_; base += 1024) {
    int i = base + (int)threadIdx.x;
    int v = (i < VOUT_) ? counts[i] : 0;
    sh[threadIdx.x] = v;
    __syncthreads();
    #pragma unroll
    for (int off = 1; off < 1024; off <<= 1) {
      int t = (threadIdx.x >= (unsigned)off) ? sh[threadIdx.x - off] : 0;
      __syncthreads();
      sh[threadIdx.x] += t;
      __syncthreads();
    }
    int excl = sh[threadIdx.x] - v;
    if (i < VOUT_) { offsets[i] = carry + excl; cursor[i] = carry + excl; }
    __syncthreads();                       // everyone done reading carry
    if (threadIdx.x == 1023) carry += sh[1023];
    __syncthreads();
  }
  if (threadIdx.x == 0) offsets[VOUT_] = carry;   // == NNZ_
}

__global__ __launch_bounds__(256) void pool_fill(const int* __restrict__ dr,
                                                 const int* __restrict__ dc,
                                                 const float* __restrict__ dd,
                                                 int* __restrict__ cursor,
                                                 int2* __restrict__ elist) {
  int e = blockIdx.x * 256 + threadIdx.x;
  if (e < NNZ_) {
    int slot = atomicAdd(&cursor[dr[e]], 1);
    elist[slot] = make_int2(dc[e], __float_as_int(dd[e]));
  }
}

// One block per output row; 8 b-groups x 32 lanes; each lane owns 4 c's (ushort4/float4).
// Fully overwrites out -> no memset needed.
__global__ __launch_bounds__(256) void pool_rows(const unsigned short* __restrict__ hbf,
                                                 const int* __restrict__ offsets,
                                                 const int2* __restrict__ elist,
                                                 float* __restrict__ out) {
  const int row = blockIdx.x;
  const int bg = threadIdx.x >> 5;     // batch 0..7
  const int lc = threadIdx.x & 31;     // c-quad 0..31
  const int s = offsets[row], e1 = offsets[row + 1];
  const unsigned short* hb = hbf + (size_t)bg * (V_ * COUT_) + lc * 4;
  float4 acc = {0.f, 0.f, 0.f, 0.f};
  for (int e = s; e < e1; ++e) {
    int2 en = elist[e];
    float d = __int_as_float(en.y);
    ushort4 v = *reinterpret_cast<const ushort4*>(hb + (size_t)en.x * COUT_);
    acc.x += d * bf2f(v.x);
    acc.y += d * bf2f(v.y);
    acc.z += d * bf2f(v.z);
    acc.w += d * bf2f(v.w);
  }
  *reinterpret_cast<float4*>(out + ((size_t)bg * VOUT_ + row) * COUT_ + lc * 4) = acc;
}

extern "C" void kernel_launch(void* const* d_in, const int* in_sizes, int n_in,
                              void* d_out, int out_size, void* d_ws, size_t ws_size,
                              hipStream_t stream) {
  const float* x    = (const float*)d_in[0];
  const float* w    = (const float*)d_in[1];
  const float* bias = (const float*)d_in[2];
  const int*   sp   = (const int*)d_in[3];
  const int*   dr   = (const int*)d_in[4];
  const int*   dc   = (const int*)d_in[5];
  const float* dd   = (const float*)d_in[6];
  float* out = (float*)d_out;

  char* ws = (char*)d_ws;
  unsigned short* wbf = (unsigned short*)ws;                       // 147,456 B
  unsigned short* xbf = (unsigned short*)(ws + 147456);            // 51,200,000 B
  unsigned short* hbf = (unsigned short*)(ws + 51347456);          // 102,400,000 B
  int*  counts  = (int*) (ws + 153747456);                         // 50,000 B
  int*  cursor  = (int*) (ws + 153797456);                         // 50,000 B
  int*  offsets = (int*) (ws + 153847456);                         // 50,004 B
  int2* elist   = (int2*)(ws + 153897464);                         // 300,000 B

  convert_w<<<288, 256, 0, stream>>>(w, wbf);
  convert_x<<<2048, 256, 0, stream>>>(x, xbf);
  hipMemsetAsync(counts, 0, VOUT_ * sizeof(int), stream);
  pool_count<<<(NNZ_ + 255) / 256, 256, 0, stream>>>(dr, counts);
  pool_scan<<<1, 1024, 0, stream>>>(counts, offsets, cursor);
  pool_fill<<<(NNZ_ + 255) / 256, 256, 0, stream>>>(dr, dc, dd, cursor, elist);
  spiral_gemm<<<M_ / 128, 256, 0, stream>>>(xbf, wbf, bias, sp, hbf);
  pool_rows<<<VOUT_, 256, 0, stream>>>(hbf, offsets, elist, out);
}